// Round 7
// baseline (390.820 us; speedup 1.0000x reference)
//
#include <hip/hip_runtime.h>

using u16 = unsigned short;
using u32 = unsigned int;

typedef __attribute__((ext_vector_type(4))) float f32x4;
typedef __attribute__((ext_vector_type(8))) short s16x8;

__device__ __forceinline__ u16 f2b(float f) {
  u32 u = __builtin_bit_cast(u32, f);
  u += 0x7FFFu + ((u >> 16) & 1u);
  return (u16)(u >> 16);
}
__device__ __forceinline__ float b2f(u16 h) {
  return __builtin_bit_cast(float, (u32)h << 16);
}
__device__ __forceinline__ void gl_lds16(const void* g, void* l) {
  __builtin_amdgcn_global_load_lds(
      (const __attribute__((address_space(1))) void*)g,
      (__attribute__((address_space(3))) void*)l, 16, 0, 0);
}

// ---- fused prep: fp32->bf16 (x|Wq|Wk|Wv), mask->bitmask, zero Lrow ----------
// blocks [0,5632): convert -> dst (xc|Wqc|Wkc|Wvc contiguous)
// blocks [5632,7680): mask bitpack -> mb (only when mb != nullptr)
// block 7680: zero Lrow[8192]
__global__ __launch_bounds__(256) void prep_k(
    const float* __restrict__ x, const float* __restrict__ Wq,
    const float* __restrict__ Wk, const float* __restrict__ Wv,
    u16* __restrict__ dst, const int* __restrict__ mask,
    u32* __restrict__ mb, float* __restrict__ Lrow) {
  int blk = blockIdx.x;
  if (blk < 5632) {
    long g = (long)(blk * 256 + threadIdx.x) * 8;   // 8-elem chunks
    const float* s;
    if (g < 8388608L)       s = x  + g;
    else if (g < 9437184L)  s = Wq + (g - 8388608L);
    else if (g < 10485760L) s = Wk + (g - 9437184L);
    else                    s = Wv + (g - 10485760L);
    f32x4 lo = *(const f32x4*)s;
    f32x4 hi = *(const f32x4*)(s + 4);
    s16x8 o;
    #pragma unroll
    for (int e = 0; e < 4; ++e) { o[e] = (short)f2b(lo[e]); o[4 + e] = (short)f2b(hi[e]); }
    *(s16x8*)(dst + g) = o;
  } else if (blk < 7680) {
    long t = (long)(blk - 5632) * 256 + threadIdx.x;   // [0, 524288)
    const int* mp = mask + t * 32;
    u32 w = 0;
    #pragma unroll
    for (int c = 0; c < 8; ++c) {
      int4 m4 = *(const int4*)(mp + c * 4);
      w |= (u32)(m4.x != 0) << (c * 4);
      w |= (u32)(m4.y != 0) << (c * 4 + 1);
      w |= (u32)(m4.z != 0) << (c * 4 + 2);
      w |= (u32)(m4.w != 0) << (c * 4 + 3);
    }
    mb[t] = w;
  } else {
    float* p = Lrow + threadIdx.x * 32;
    #pragma unroll
    for (int c = 0; c < 8; ++c) *(f32x4*)(p + c * 4) = (f32x4){0.f, 0.f, 0.f, 0.f};
  }
}

// ---- m97-style NT GEMM: D[m][n] = sum_k A[m][k]*B[n][k], 128x128x32 tiles ----
// z = blockIdx.z batches via element strides za/zb/ze.
// EPI 0: QKV proj (B = Wq|Wk|Wv per N-tile; +fp32 bias; bf16 Q[b][s][h],
//        K[b][s][h], Vt[b][d][s]).
// EPI 1: scores. Fused path (mbits): e = bit ? exp(s/32) : 0 -> bf16 Sc; fp32
//        row-sums atomicAdd into Lrow (softmax denominators). Legacy path
//        (mbits==null): s/32, mask==0 -> -inf.
// EPI 2: PV -> fp32 out; fused path divides by Lrow[q] (softmax normalize).
template<int EPI>
__global__ __launch_bounds__(256) void gemm_bt(
    const u16* __restrict__ A, const u16* __restrict__ B0,
    const u16* __restrict__ W2, const u16* __restrict__ W3,
    int lda, int ldb, int K, long za, long zb, long ze,
    const float* __restrict__ bq, const float* __restrict__ bk, const float* __restrict__ bv,
    u16* __restrict__ qw, u16* __restrict__ kw, u16* __restrict__ vt,
    const int* __restrict__ mask, const u32* __restrict__ mbits,
    float* __restrict__ Lrow, u16* __restrict__ sc, float* __restrict__ outO)
{
  __shared__ __align__(16) u16 lds[128 * 32 * 2];  // A tile | B tile, 16 KB
  const int tid = threadIdx.x;
  const int wave = tid >> 6, lane = tid & 63;
  const int wr = wave >> 1, wc = wave & 1;
  const int m0 = blockIdx.y * 128, n0 = blockIdx.x * 128;
  const long z = blockIdx.z;
  A += z * za;

  const u16* Bsrc = B0;
  int nbase = n0;
  if constexpr (EPI == 0) {
    Bsrc = (n0 < 1024) ? B0 : (n0 < 2048) ? W2 : W3;
    nbase = n0 & 1023;
  }
  Bsrc += z * zb;

  u16* As = lds;
  u16* Bs = lds + 128 * 32;

  f32x4 acc[4][4];
  const f32x4 fz = {0.f, 0.f, 0.f, 0.f};
  #pragma unroll
  for (int i = 0; i < 4; ++i)
    #pragma unroll
    for (int j = 0; j < 4; ++j) acc[i][j] = fz;

  const int frow = lane & 15;   // m (or n) index within 16x16 tile
  const int q    = lane >> 4;   // k-quarter (8 elems each)

  for (int k0 = 0; k0 < K; k0 += 32) {
    __syncthreads();   // prev iteration's ds_reads done before overwrite
    #pragma unroll
    for (int call = 0; call < 2; ++call) {
      int c = call * 256 + tid;                  // LDS 16B chunk id, 512/tile
      int row = c >> 2;
      int kc = (c & 3) ^ (row & 3);              // XOR-swizzled source chunk
      const u16* ga = A    + (size_t)(m0    + row) * lda + (k0 + kc * 8);
      const u16* gb = Bsrc + (size_t)(nbase + row) * ldb + (k0 + kc * 8);
      u16* la = As + (size_t)(call * 256 + wave * 64) * 8;   // wave-uniform base
      u16* lb = Bs + (size_t)(call * 256 + wave * 64) * 8;
      gl_lds16(ga, la);
      gl_lds16(gb, lb);
    }
    __syncthreads();   // vmcnt drain + visibility

    s16x8 af[4], bf[4];
    #pragma unroll
    for (int i = 0; i < 4; ++i) {
      int lr = wr * 64 + i * 16 + frow;
      af[i] = *(const s16x8*)(As + lr * 32 + ((q ^ (lr & 3)) << 3));
    }
    #pragma unroll
    for (int j = 0; j < 4; ++j) {
      int lc = wc * 64 + j * 16 + frow;
      bf[j] = *(const s16x8*)(Bs + lc * 32 + ((q ^ (lc & 3)) << 3));
    }
    #pragma unroll
    for (int i = 0; i < 4; ++i)
      #pragma unroll
      for (int j = 0; j < 4; ++j)
        acc[i][j] = __builtin_amdgcn_mfma_f32_16x16x32_bf16(af[i], bf[j], acc[i][j], 0, 0, 0);
  }

  // epilogue: C/D layout col=lane&15, row=(lane>>4)*4+reg  (m89-verified)
  const int r0 = (lane >> 4) * 4;
  const int ccol = lane & 15;

  if constexpr (EPI == 0) {
    #pragma unroll
    for (int i = 0; i < 4; ++i) {
      #pragma unroll
      for (int j = 0; j < 4; ++j) {
        #pragma unroll
        for (int r = 0; r < 4; ++r) {
          int R = m0 + wr * 64 + i * 16 + r0 + r;
          int C = n0 + wc * 64 + j * 16 + ccol;
          float v = acc[i][j][r];
          int sec = C >> 10, nl = C & 1023;
          v += (sec == 0) ? bq[nl] : (sec == 1) ? bk[nl] : bv[nl];
          u16 o = f2b(v);
          int b = R >> 11, s = R & 2047;
          if (sec == 0)      qw[(size_t)R * 1024 + nl] = o;
          else if (sec == 1) kw[(size_t)R * 1024 + nl] = o;
          else               vt[(size_t)b * 2097152u + (size_t)nl * 2048 + s] = o;
        }
      }
    }
  } else if constexpr (EPI == 1) {
    if (mbits) {
      float rs[4][4];
      #pragma unroll
      for (int i = 0; i < 4; ++i)
        #pragma unroll
        for (int r = 0; r < 4; ++r) rs[i][r] = 0.f;
      #pragma unroll
      for (int i = 0; i < 4; ++i) {
        #pragma unroll
        for (int j = 0; j < 4; ++j) {
          #pragma unroll
          for (int r = 0; r < 4; ++r) {
            int R = m0 + wr * 64 + i * 16 + r0 + r;
            int C = n0 + wc * 64 + j * 16 + ccol;
            float v = acc[i][j][r] * 0.03125f;
            size_t idx = (size_t)(z * ze) + (size_t)R * 2048 + C;
            u32 w = mbits[idx >> 5];
            float e = ((w >> (idx & 31)) & 1u) ? __expf(v) : 0.f;
            u16 eb = f2b(e);
            sc[idx] = eb;
            rs[i][r] += b2f(eb);   // sum the *rounded* numerators
          }
        }
      }
      #pragma unroll
      for (int i = 0; i < 4; ++i) {
        #pragma unroll
        for (int r = 0; r < 4; ++r) {
          float s_ = rs[i][r];
          s_ += __shfl_xor(s_, 1);
          s_ += __shfl_xor(s_, 2);
          s_ += __shfl_xor(s_, 4);
          s_ += __shfl_xor(s_, 8);
          if ((lane & 15) == 0)
            atomicAdd(Lrow + z * 2048 + m0 + wr * 64 + i * 16 + r0 + r, s_);
        }
      }
    } else {
      #pragma unroll
      for (int i = 0; i < 4; ++i)
        #pragma unroll
        for (int j = 0; j < 4; ++j)
          #pragma unroll
          for (int r = 0; r < 4; ++r) {
            int R = m0 + wr * 64 + i * 16 + r0 + r;
            int C = n0 + wc * 64 + j * 16 + ccol;
            float v = acc[i][j][r] * 0.03125f;
            size_t idx = (size_t)(z * ze) + (size_t)R * 2048 + C;
            if (mask[idx] == 0) v = -__builtin_inff();
            sc[idx] = f2b(v);
          }
    }
  } else {
    #pragma unroll
    for (int i = 0; i < 4; ++i) {
      #pragma unroll
      for (int r = 0; r < 4; ++r) {
        int R = m0 + wr * 64 + i * 16 + r0 + r;
        float inv = Lrow ? (1.f / Lrow[z * 2048 + R]) : 1.f;
        #pragma unroll
        for (int j = 0; j < 4; ++j) {
          int C = n0 + wc * 64 + j * 16 + ccol;
          outO[(size_t)(z * ze) + (size_t)R * 1024 + C] = acc[i][j][r] * inv;
        }
      }
    }
  }
}

// ---- legacy row softmax (fallback path only) --------------------------------
__global__ __launch_bounds__(256) void softmax_k(u16* __restrict__ Sc) {
  __shared__ float red[8];
  u16* p = Sc + (size_t)blockIdx.x * 2048;
  const int tid = threadIdx.x;
  const int lane = tid & 63, wv = tid >> 6;
  s16x8 u = *(const s16x8*)(p + tid * 8);
  float v[8];
  #pragma unroll
  for (int e = 0; e < 8; ++e) v[e] = b2f((u16)u[e]);
  float mx = v[0];
  #pragma unroll
  for (int e = 1; e < 8; ++e) mx = fmaxf(mx, v[e]);
  #pragma unroll
  for (int off = 32; off > 0; off >>= 1) mx = fmaxf(mx, __shfl_xor(mx, off));
  if (lane == 0) red[wv] = mx;
  __syncthreads();
  mx = fmaxf(fmaxf(red[0], red[1]), fmaxf(red[2], red[3]));
  float s = 0.f;
  #pragma unroll
  for (int e = 0; e < 8; ++e) { v[e] = __expf(v[e] - mx); s += v[e]; }
  #pragma unroll
  for (int off = 32; off > 0; off >>= 1) s += __shfl_xor(s, off);
  if (lane == 0) red[4 + wv] = s;
  __syncthreads();
  s = (red[4] + red[5]) + (red[6] + red[7]);
  float inv = 1.f / s;
  s16x8 o;
  #pragma unroll
  for (int e = 0; e < 8; ++e) o[e] = (short)f2b(v[e] * inv);
  *(s16x8*)(p + tid * 8) = o;
}

extern "C" void kernel_launch(void* const* d_in, const int* in_sizes, int n_in,
                              void* d_out, int out_size, void* d_ws, size_t ws_size,
                              hipStream_t stream) {
  const float* x  = (const float*)d_in[0];
  const int* mask = (const int*)d_in[1];
  const float* Wq = (const float*)d_in[2];
  const float* bq = (const float*)d_in[3];
  const float* Wk = (const float*)d_in[4];
  const float* bk = (const float*)d_in[5];
  const float* Wv = (const float*)d_in[6];
  const float* bv = (const float*)d_in[7];
  float* out = (float*)d_out;
  char* ws = (char*)d_ws;

  if (ws_size >= (size_t)112 * 1024 * 1024) {
    // ---- fused path: 106 MB ws ----
    float* Lrow = (float*)ws;              // [4][2048] fp32 = 32 KB
    u32* Mb  = (u32*)(ws + (1u << 20));    // bitmask, 2 MB
    u16* xc  = (u16*)(ws + (4u << 20));    // [8192][1024] 16 MB
    u16* Wqc = (u16*)(ws + (20u << 20));
    u16* Wkc = (u16*)(ws + (22u << 20));
    u16* Wvc = (u16*)(ws + (24u << 20));
    u16* Qw  = (u16*)(ws + (26u << 20));   // 16 MB
    u16* Kw  = (u16*)(ws + (42u << 20));   // 16 MB
    u16* Vt  = (u16*)(ws + (58u << 20));   // 16 MB
    u16* Sc  = (u16*)(ws + (74u << 20));   // 32 MB -> ends at 106 MB

    prep_k<<<7681, 256, 0, stream>>>(x, Wq, Wk, Wv, xc, mask, Mb, Lrow);
    gemm_bt<0><<<dim3(24, 64, 1), 256, 0, stream>>>(
        xc, Wqc, Wkc, Wvc, 1024, 1024, 1024, 0, 0, 0,
        bq, bk, bv, Qw, Kw, Vt, nullptr, nullptr, nullptr, nullptr, nullptr);
    gemm_bt<1><<<dim3(16, 16, 4), 256, 0, stream>>>(
        Qw, Kw, nullptr, nullptr, 1024, 1024, 1024, 2097152, 2097152, 4194304,
        nullptr, nullptr, nullptr, nullptr, nullptr, nullptr,
        nullptr, Mb, Lrow, Sc, nullptr);
    gemm_bt<2><<<dim3(8, 16, 4), 256, 0, stream>>>(
        Sc, Vt, nullptr, nullptr, 2048, 2048, 2048, 4194304, 2097152, 2097152,
        nullptr, nullptr, nullptr, nullptr, nullptr, nullptr,
        nullptr, nullptr, Lrow, nullptr, out);
  } else {
    // ---- round-6 fallback: 102 MB ws ----
    u16* xc  = (u16*)ws;
    u16* Wqc = (u16*)(ws + (16u << 20));
    u16* Wkc = (u16*)(ws + (18u << 20));
    u16* Wvc = (u16*)(ws + (20u << 20));
    u16* Qw  = (u16*)(ws + (22u << 20));
    u16* Kw  = (u16*)(ws + (38u << 20));
    u16* Vt  = (u16*)(ws + (54u << 20));
    u16* Sc  = (u16*)(ws + (70u << 20));

    prep_k<<<5632, 256, 0, stream>>>(x, Wq, Wk, Wv, xc, mask, nullptr, nullptr);
    gemm_bt<0><<<dim3(24, 64, 1), 256, 0, stream>>>(
        xc, Wqc, Wkc, Wvc, 1024, 1024, 1024, 0, 0, 0,
        bq, bk, bv, Qw, Kw, Vt, nullptr, nullptr, nullptr, nullptr, nullptr);
    gemm_bt<1><<<dim3(16, 16, 4), 256, 0, stream>>>(
        Qw, Kw, nullptr, nullptr, 1024, 1024, 1024, 2097152, 2097152, 4194304,
        nullptr, nullptr, nullptr, nullptr, nullptr, nullptr,
        mask, nullptr, nullptr, Sc, nullptr);
    softmax_k<<<8192, 256, 0, stream>>>(Sc);
    gemm_bt<2><<<dim3(8, 16, 4), 256, 0, stream>>>(
        Sc, Vt, nullptr, nullptr, 2048, 2048, 2048, 4194304, 2097152, 2097152,
        nullptr, nullptr, nullptr, nullptr, nullptr, nullptr,
        nullptr, nullptr, nullptr, nullptr, out);
  }
}

// Round 8
// 366.331 us; speedup vs baseline: 1.0668x; 1.0668x over previous
//
#include <hip/hip_runtime.h>

using u16 = unsigned short;
using u32 = unsigned int;

typedef __attribute__((ext_vector_type(4))) float f32x4;
typedef __attribute__((ext_vector_type(8))) short s16x8;

__device__ __forceinline__ u16 f2b(float f) {
  u32 u = __builtin_bit_cast(u32, f);
  u += 0x7FFFu + ((u >> 16) & 1u);
  return (u16)(u >> 16);
}
__device__ __forceinline__ float b2f(u16 h) {
  return __builtin_bit_cast(float, (u32)h << 16);
}
__device__ __forceinline__ void gl_lds16(const void* g, void* l) {
  __builtin_amdgcn_global_load_lds(
      (const __attribute__((address_space(1))) void*)g,
      (__attribute__((address_space(3))) void*)l, 16, 0, 0);
}

// ---- fused fp32 -> bf16 conversion: x | Wq | Wk | Wv -> contiguous dst ------
__global__ __launch_bounds__(256) void convert4_k(
    const float* __restrict__ x, const float* __restrict__ Wq,
    const float* __restrict__ Wk, const float* __restrict__ Wv,
    u16* __restrict__ dst) {
  long g = (long)(blockIdx.x * 256 + threadIdx.x) * 8;   // 8-elem chunks
  const float* s;
  if (g < 8388608L)       s = x  + g;
  else if (g < 9437184L)  s = Wq + (g - 8388608L);
  else if (g < 10485760L) s = Wk + (g - 9437184L);
  else                    s = Wv + (g - 10485760L);
  f32x4 lo = *(const f32x4*)s;
  f32x4 hi = *(const f32x4*)(s + 4);
  s16x8 o;
  #pragma unroll
  for (int e = 0; e < 4; ++e) { o[e] = (short)f2b(lo[e]); o[4 + e] = (short)f2b(hi[e]); }
  *(s16x8*)(dst + g) = o;
}

// ---- NT GEMM, 128x128 tile, BK=64 (32 MFMA/wave between barrier pairs) ------
// D[m][n] = sum_k A[m][k]*B[n][k].  z batches via element strides za/zb/ze.
// EPI 0: QKV proj (B = Wq|Wk|Wv per N-tile; +fp32 bias; bf16 Q[b][s][h],
//        K[b][s][h], Vt[b][d][s]).  EPI 1: scores (*1/32, mask==0 -> -inf).
// EPI 2: PV -> fp32 out.
template<int EPI>
__global__ __launch_bounds__(256) void gemm_bt(
    const u16* __restrict__ A, const u16* __restrict__ B0,
    const u16* __restrict__ W2, const u16* __restrict__ W3,
    int lda, int ldb, int K, long za, long zb, long ze,
    const float* __restrict__ bq, const float* __restrict__ bk, const float* __restrict__ bv,
    u16* __restrict__ qw, u16* __restrict__ kw, u16* __restrict__ vt,
    const int* __restrict__ mask, u16* __restrict__ sc, float* __restrict__ outO)
{
  __shared__ __align__(16) u16 lds[128 * 64 * 2];  // A tile | B tile, 32 KB
  const int tid = threadIdx.x;
  const int wave = tid >> 6, lane = tid & 63;
  const int wr = wave >> 1, wc = wave & 1;
  const int m0 = blockIdx.y * 128, n0 = blockIdx.x * 128;
  const long z = blockIdx.z;
  A += z * za;

  const u16* Bsrc = B0;
  int nbase = n0;
  if constexpr (EPI == 0) {
    Bsrc = (n0 < 1024) ? B0 : (n0 < 2048) ? W2 : W3;
    nbase = n0 & 1023;
  }
  Bsrc += z * zb;

  u16* As = lds;
  u16* Bs = lds + 128 * 64;

  f32x4 acc[4][4];
  const f32x4 fz = {0.f, 0.f, 0.f, 0.f};
  #pragma unroll
  for (int i = 0; i < 4; ++i)
    #pragma unroll
    for (int j = 0; j < 4; ++j) acc[i][j] = fz;

  const int frow = lane & 15;   // m (or n) index within 16x16 tile
  const int q    = lane >> 4;   // k-quarter within a 32-k half (8 elems)

  for (int k0 = 0; k0 < K; k0 += 64) {
    __syncthreads();   // prev iteration's ds_reads done before overwrite
    #pragma unroll
    for (int call = 0; call < 4; ++call) {
      int c = call * 256 + tid;        // 16B chunk id, 1024 per 128x64 tile
      int row = c >> 3;                // 8 chunks per 64-elem row
      int kc  = c & 7;
      const u16* ga = A    + (size_t)(m0    + row) * lda + (k0 + kc * 8);
      const u16* gb = Bsrc + (size_t)(nbase + row) * ldb + (k0 + kc * 8);
      // LDS dest: wave-uniform base + lane*16B (HW-fixed map); c*16B matches.
      gl_lds16(ga, As + (size_t)c * 8);
      gl_lds16(gb, Bs + (size_t)c * 8);
    }
    __syncthreads();   // vmcnt drain + visibility

    #pragma unroll
    for (int t = 0; t < 2; ++t) {      // two 32-k halves per staged tile
      s16x8 af[4], bf[4];
      #pragma unroll
      for (int i = 0; i < 4; ++i)
        af[i] = *(const s16x8*)(As + (wr * 64 + i * 16 + frow) * 64 + t * 32 + q * 8);
      #pragma unroll
      for (int j = 0; j < 4; ++j)
        bf[j] = *(const s16x8*)(Bs + (wc * 64 + j * 16 + frow) * 64 + t * 32 + q * 8);
      #pragma unroll
      for (int i = 0; i < 4; ++i)
        #pragma unroll
        for (int j = 0; j < 4; ++j)
          acc[i][j] = __builtin_amdgcn_mfma_f32_16x16x32_bf16(af[i], bf[j], acc[i][j], 0, 0, 0);
    }
  }

  // epilogue: C/D layout col=lane&15, row=(lane>>4)*4+reg  (m89-verified)
  const int r0 = (lane >> 4) * 4;
  const int ccol = lane & 15;
  #pragma unroll
  for (int i = 0; i < 4; ++i) {
    #pragma unroll
    for (int j = 0; j < 4; ++j) {
      #pragma unroll
      for (int r = 0; r < 4; ++r) {
        int R = m0 + wr * 64 + i * 16 + r0 + r;   // row: (b,)s / q index
        int C = n0 + wc * 64 + j * 16 + ccol;     // col: feature / k / d index
        float v = acc[i][j][r];
        if constexpr (EPI == 0) {
          int sec = C >> 10, nl = C & 1023;
          v += (sec == 0) ? bq[nl] : (sec == 1) ? bk[nl] : bv[nl];
          u16 o = f2b(v);
          int b = R >> 11, s = R & 2047;
          if (sec == 0)      qw[(size_t)R * 1024 + nl] = o;               // Q[b][s][h]
          else if (sec == 1) kw[(size_t)R * 1024 + nl] = o;               // K[b][s][h]
          else               vt[(size_t)b * 2097152u + (size_t)nl * 2048 + s] = o; // Vt[b][d][s]
        } else if constexpr (EPI == 1) {
          v *= 0.03125f;  // 1/sqrt(1024)
          size_t idx = (size_t)(z * ze) + (size_t)R * 2048 + C;
          if (mask[idx] == 0) v = -__builtin_inff();
          sc[idx] = f2b(v);
        } else {
          outO[(size_t)(z * ze) + (size_t)R * 1024 + C] = v;   // fp32 out
        }
      }
    }
  }
}

// ---- row softmax over 2048 bf16, in place, fp32 internal --------------------
__global__ __launch_bounds__(256) void softmax_k(u16* __restrict__ Sc) {
  __shared__ float red[8];
  u16* p = Sc + (size_t)blockIdx.x * 2048;
  const int tid = threadIdx.x;
  const int lane = tid & 63, wv = tid >> 6;
  s16x8 u = *(const s16x8*)(p + tid * 8);
  float v[8];
  #pragma unroll
  for (int e = 0; e < 8; ++e) v[e] = b2f((u16)u[e]);
  float mx = v[0];
  #pragma unroll
  for (int e = 1; e < 8; ++e) mx = fmaxf(mx, v[e]);
  #pragma unroll
  for (int off = 32; off > 0; off >>= 1) mx = fmaxf(mx, __shfl_xor(mx, off));
  if (lane == 0) red[wv] = mx;
  __syncthreads();
  mx = fmaxf(fmaxf(red[0], red[1]), fmaxf(red[2], red[3]));
  float s = 0.f;
  #pragma unroll
  for (int e = 0; e < 8; ++e) { v[e] = __expf(v[e] - mx); s += v[e]; }
  #pragma unroll
  for (int off = 32; off > 0; off >>= 1) s += __shfl_xor(s, off);
  if (lane == 0) red[4 + wv] = s;
  __syncthreads();
  s = (red[4] + red[5]) + (red[6] + red[7]);
  float inv = 1.f / s;
  s16x8 o;
  #pragma unroll
  for (int e = 0; e < 8; ++e) o[e] = (short)f2b(v[e] * inv);
  *(s16x8*)(p + tid * 8) = o;
}

extern "C" void kernel_launch(void* const* d_in, const int* in_sizes, int n_in,
                              void* d_out, int out_size, void* d_ws, size_t ws_size,
                              hipStream_t stream) {
  const float* x  = (const float*)d_in[0];
  const int* mask = (const int*)d_in[1];
  const float* Wq = (const float*)d_in[2];
  const float* bq = (const float*)d_in[3];
  const float* Wk = (const float*)d_in[4];
  const float* bk = (const float*)d_in[5];
  const float* Wv = (const float*)d_in[6];
  const float* bv = (const float*)d_in[7];
  float* out = (float*)d_out;
  char* ws = (char*)d_ws;   // ws_size >= 104 MB established in round 5

  u16* xc  = (u16*)ws;                   // [8192][1024]  16 MB
  u16* Wqc = (u16*)(ws + (16u << 20));   // 2 MB each (contiguous after xc)
  u16* Wkc = (u16*)(ws + (18u << 20));
  u16* Wvc = (u16*)(ws + (20u << 20));
  u16* Qw  = (u16*)(ws + (22u << 20));   // [4][2048][1024] 16 MB
  u16* Kw  = (u16*)(ws + (38u << 20));   // 16 MB
  u16* Vt  = (u16*)(ws + (54u << 20));   // [4][1024][2048] 16 MB
  u16* Sc  = (u16*)(ws + (70u << 20));   // [4][2048][2048] 32 MB -> 102 MB

  convert4_k<<<5632, 256, 0, stream>>>(x, Wq, Wk, Wv, xc);

  // QKV: M=8192 (b,s), N=3072 (q|k|v), K=1024
  gemm_bt<0><<<dim3(24, 64, 1), 256, 0, stream>>>(
      xc, Wqc, Wkc, Wvc, 1024, 1024, 1024, 0, 0, 0,
      bq, bk, bv, Qw, Kw, Vt, nullptr, nullptr, nullptr);
  // scores: per-z M=2048 (q), N=2048 (k), K=1024
  gemm_bt<1><<<dim3(16, 16, 4), 256, 0, stream>>>(
      Qw, Kw, nullptr, nullptr, 1024, 1024, 1024, 2097152, 2097152, 4194304,
      nullptr, nullptr, nullptr, nullptr, nullptr, nullptr, mask, Sc, nullptr);
  softmax_k<<<8192, 256, 0, stream>>>(Sc);
  // PV: per-z M=2048 (q), N=1024 (d), K=2048
  gemm_bt<2><<<dim3(8, 16, 4), 256, 0, stream>>>(
      Sc, Vt, nullptr, nullptr, 2048, 2048, 2048, 4194304, 2097152, 2097152,
      nullptr, nullptr, nullptr, nullptr, nullptr, nullptr, nullptr, nullptr, out);
}

// Round 9
// 338.371 us; speedup vs baseline: 1.1550x; 1.0826x over previous
//
#include <hip/hip_runtime.h>

using u16 = unsigned short;
using u32 = unsigned int;

typedef __attribute__((ext_vector_type(4))) float f32x4;
typedef __attribute__((ext_vector_type(8))) short s16x8;

__device__ __forceinline__ u16 f2b(float f) {
  u32 u = __builtin_bit_cast(u32, f);
  u += 0x7FFFu + ((u >> 16) & 1u);
  return (u16)(u >> 16);
}
__device__ __forceinline__ float b2f(u16 h) {
  return __builtin_bit_cast(float, (u32)h << 16);
}
__device__ __forceinline__ void gl_lds16(const void* g, void* l) {
  __builtin_amdgcn_global_load_lds(
      (const __attribute__((address_space(1))) void*)g,
      (__attribute__((address_space(3))) void*)l, 16, 0, 0);
}

// ---- fused fp32 -> bf16 conversion: x | Wq | Wk | Wv -> contiguous dst ------
__global__ __launch_bounds__(256) void convert4_k(
    const float* __restrict__ x, const float* __restrict__ Wq,
    const float* __restrict__ Wk, const float* __restrict__ Wv,
    u16* __restrict__ dst) {
  long g = (long)(blockIdx.x * 256 + threadIdx.x) * 8;   // 8-elem chunks
  const float* s;
  if (g < 8388608L)       s = x  + g;
  else if (g < 9437184L)  s = Wq + (g - 8388608L);
  else if (g < 10485760L) s = Wk + (g - 9437184L);
  else                    s = Wv + (g - 10485760L);
  f32x4 lo = *(const f32x4*)s;
  f32x4 hi = *(const f32x4*)(s + 4);
  s16x8 o;
  #pragma unroll
  for (int e = 0; e < 4; ++e) { o[e] = (short)f2b(lo[e]); o[4 + e] = (short)f2b(hi[e]); }
  *(s16x8*)(dst + g) = o;
}

// ---- NT GEMM, 128x128 tile, BK=64, 3-bit XOR bank swizzle -------------------
// D[m][n] = sum_k A[m][k]*B[n][k].  z batches via element strides za/zb/ze.
// LDS chunk (row, lc) holds global 16B chunk (row, lc ^ (row&7)): with row
// stride 128 B (bank-invariant), lc spans all 8 four-bank groups across the
// 16 frow lanes -> 8 lanes/group (the BK=32 conflict level) instead of 16.
// EPI 0: QKV proj (B = Wq|Wk|Wv per N-tile; +fp32 bias; bf16 Q[b][s][h],
//        K[b][s][h], Vt[b][d][s]).  EPI 1: scores (*1/32, mask==0 -> -inf).
// EPI 2: PV -> fp32 out.
template<int EPI>
__global__ __launch_bounds__(256) void gemm_bt(
    const u16* __restrict__ A, const u16* __restrict__ B0,
    const u16* __restrict__ W2, const u16* __restrict__ W3,
    int lda, int ldb, int K, long za, long zb, long ze,
    const float* __restrict__ bq, const float* __restrict__ bk, const float* __restrict__ bv,
    u16* __restrict__ qw, u16* __restrict__ kw, u16* __restrict__ vt,
    const int* __restrict__ mask, u16* __restrict__ sc, float* __restrict__ outO)
{
  __shared__ __align__(16) u16 lds[128 * 64 * 2];  // A tile | B tile, 32 KB
  const int tid = threadIdx.x;
  const int wave = tid >> 6, lane = tid & 63;
  const int wr = wave >> 1, wc = wave & 1;
  const int m0 = blockIdx.y * 128, n0 = blockIdx.x * 128;
  const long z = blockIdx.z;
  A += z * za;

  const u16* Bsrc = B0;
  int nbase = n0;
  if constexpr (EPI == 0) {
    Bsrc = (n0 < 1024) ? B0 : (n0 < 2048) ? W2 : W3;
    nbase = n0 & 1023;
  }
  Bsrc += z * zb;

  u16* As = lds;
  u16* Bs = lds + 128 * 64;

  f32x4 acc[4][4];
  const f32x4 fz = {0.f, 0.f, 0.f, 0.f};
  #pragma unroll
  for (int i = 0; i < 4; ++i)
    #pragma unroll
    for (int j = 0; j < 4; ++j) acc[i][j] = fz;

  const int frow = lane & 15;   // m (or n) index within 16x16 tile
  const int q    = lane >> 4;   // k-quarter within a 32-k half (8 elems)

  for (int k0 = 0; k0 < K; k0 += 64) {
    __syncthreads();   // prev iteration's ds_reads done before overwrite
    #pragma unroll
    for (int call = 0; call < 4; ++call) {
      int c = call * 256 + tid;        // LDS 16B chunk id, 1024 per 128x64 tile
      int row = c >> 3;                // 8 chunks per 64-elem row
      int kc  = (c & 7) ^ (row & 7);   // XOR-swizzled source chunk
      const u16* ga = A    + (size_t)(m0    + row) * lda + (k0 + kc * 8);
      const u16* gb = Bsrc + (size_t)(nbase + row) * ldb + (k0 + kc * 8);
      // LDS dest: wave-uniform base + lane*16B (HW-fixed map); c*16B matches.
      gl_lds16(ga, As + (size_t)c * 8);
      gl_lds16(gb, Bs + (size_t)c * 8);
    }
    __syncthreads();   // vmcnt drain + visibility

    #pragma unroll
    for (int t = 0; t < 2; ++t) {      // two 32-k halves per staged tile
      s16x8 af[4], bf[4];
      #pragma unroll
      for (int i = 0; i < 4; ++i) {
        int lr = wr * 64 + i * 16 + frow;
        af[i] = *(const s16x8*)(As + lr * 64 + (((t * 4 + q) ^ (lr & 7)) << 3));
      }
      #pragma unroll
      for (int j = 0; j < 4; ++j) {
        int lc = wc * 64 + j * 16 + frow;
        bf[j] = *(const s16x8*)(Bs + lc * 64 + (((t * 4 + q) ^ (lc & 7)) << 3));
      }
      #pragma unroll
      for (int i = 0; i < 4; ++i)
        #pragma unroll
        for (int j = 0; j < 4; ++j)
          acc[i][j] = __builtin_amdgcn_mfma_f32_16x16x32_bf16(af[i], bf[j], acc[i][j], 0, 0, 0);
    }
  }

  // epilogue: C/D layout col=lane&15, row=(lane>>4)*4+reg  (m89-verified)
  const int r0 = (lane >> 4) * 4;
  const int ccol = lane & 15;
  #pragma unroll
  for (int i = 0; i < 4; ++i) {
    #pragma unroll
    for (int j = 0; j < 4; ++j) {
      #pragma unroll
      for (int r = 0; r < 4; ++r) {
        int R = m0 + wr * 64 + i * 16 + r0 + r;   // row: (b,)s / q index
        int C = n0 + wc * 64 + j * 16 + ccol;     // col: feature / k / d index
        float v = acc[i][j][r];
        if constexpr (EPI == 0) {
          int sec = C >> 10, nl = C & 1023;
          v += (sec == 0) ? bq[nl] : (sec == 1) ? bk[nl] : bv[nl];
          u16 o = f2b(v);
          int b = R >> 11, s = R & 2047;
          if (sec == 0)      qw[(size_t)R * 1024 + nl] = o;               // Q[b][s][h]
          else if (sec == 1) kw[(size_t)R * 1024 + nl] = o;               // K[b][s][h]
          else               vt[(size_t)b * 2097152u + (size_t)nl * 2048 + s] = o; // Vt[b][d][s]
        } else if constexpr (EPI == 1) {
          v *= 0.03125f;  // 1/sqrt(1024)
          size_t idx = (size_t)(z * ze) + (size_t)R * 2048 + C;
          if (mask[idx] == 0) v = -__builtin_inff();
          sc[idx] = f2b(v);
        } else {
          outO[(size_t)(z * ze) + (size_t)R * 1024 + C] = v;   // fp32 out
        }
      }
    }
  }
}

// ---- row softmax over 2048 bf16, in place, fp32 internal --------------------
__global__ __launch_bounds__(256) void softmax_k(u16* __restrict__ Sc) {
  __shared__ float red[8];
  u16* p = Sc + (size_t)blockIdx.x * 2048;
  const int tid = threadIdx.x;
  const int lane = tid & 63, wv = tid >> 6;
  s16x8 u = *(const s16x8*)(p + tid * 8);
  float v[8];
  #pragma unroll
  for (int e = 0; e < 8; ++e) v[e] = b2f((u16)u[e]);
  float mx = v[0];
  #pragma unroll
  for (int e = 1; e < 8; ++e) mx = fmaxf(mx, v[e]);
  #pragma unroll
  for (int off = 32; off > 0; off >>= 1) mx = fmaxf(mx, __shfl_xor(mx, off));
  if (lane == 0) red[wv] = mx;
  __syncthreads();
  mx = fmaxf(fmaxf(red[0], red[1]), fmaxf(red[2], red[3]));
  float s = 0.f;
  #pragma unroll
  for (int e = 0; e < 8; ++e) { v[e] = __expf(v[e] - mx); s += v[e]; }
  #pragma unroll
  for (int off = 32; off > 0; off >>= 1) s += __shfl_xor(s, off);
  if (lane == 0) red[4 + wv] = s;
  __syncthreads();
  s = (red[4] + red[5]) + (red[6] + red[7]);
  float inv = 1.f / s;
  s16x8 o;
  #pragma unroll
  for (int e = 0; e < 8; ++e) o[e] = (short)f2b(v[e] * inv);
  *(s16x8*)(p + tid * 8) = o;
}

extern "C" void kernel_launch(void* const* d_in, const int* in_sizes, int n_in,
                              void* d_out, int out_size, void* d_ws, size_t ws_size,
                              hipStream_t stream) {
  const float* x  = (const float*)d_in[0];
  const int* mask = (const int*)d_in[1];
  const float* Wq = (const float*)d_in[2];
  const float* bq = (const float*)d_in[3];
  const float* Wk = (const float*)d_in[4];
  const float* bk = (const float*)d_in[5];
  const float* Wv = (const float*)d_in[6];
  const float* bv = (const float*)d_in[7];
  float* out = (float*)d_out;
  char* ws = (char*)d_ws;   // ws_size >= 104 MB established in round 5

  u16* xc  = (u16*)ws;                   // [8192][1024]  16 MB
  u16* Wqc = (u16*)(ws + (16u << 20));   // 2 MB each (contiguous after xc)
  u16* Wkc = (u16*)(ws + (18u << 20));
  u16* Wvc = (u16*)(ws + (20u << 20));
  u16* Qw  = (u16*)(ws + (22u << 20));   // [4][2048][1024] 16 MB
  u16* Kw  = (u16*)(ws + (38u << 20));   // 16 MB
  u16* Vt  = (u16*)(ws + (54u << 20));   // [4][1024][2048] 16 MB
  u16* Sc  = (u16*)(ws + (70u << 20));   // [4][2048][2048] 32 MB -> 102 MB

  convert4_k<<<5632, 256, 0, stream>>>(x, Wq, Wk, Wv, xc);

  // QKV: M=8192 (b,s), N=3072 (q|k|v), K=1024
  gemm_bt<0><<<dim3(24, 64, 1), 256, 0, stream>>>(
      xc, Wqc, Wkc, Wvc, 1024, 1024, 1024, 0, 0, 0,
      bq, bk, bv, Qw, Kw, Vt, nullptr, nullptr, nullptr);
  // scores: per-z M=2048 (q), N=2048 (k), K=1024
  gemm_bt<1><<<dim3(16, 16, 4), 256, 0, stream>>>(
      Qw, Kw, nullptr, nullptr, 1024, 1024, 1024, 2097152, 2097152, 4194304,
      nullptr, nullptr, nullptr, nullptr, nullptr, nullptr, mask, Sc, nullptr);
  softmax_k<<<8192, 256, 0, stream>>>(Sc);
  // PV: per-z M=2048 (q), N=1024 (d), K=2048
  gemm_bt<2><<<dim3(8, 16, 4), 256, 0, stream>>>(
      Sc, Vt, nullptr, nullptr, 2048, 2048, 2048, 4194304, 2097152, 2097152,
      nullptr, nullptr, nullptr, nullptr, nullptr, nullptr, nullptr, nullptr, out);
}